// Round 1
// 228.215 us; speedup vs baseline: 1.0329x; 1.0329x over previous
//
#include <hip/hip_runtime.h>
#include <cstdint>
#include <cstddef>

// Problem shape (fixed by the reference): B=8, S=2048, D=512, fp32 in/out.
#define B_ 8
#define S_ 2048
#define D_ 512

typedef float f32x4 __attribute__((ext_vector_type(4)));
typedef __bf16 bf16x8 __attribute__((ext_vector_type(8)));

// fp32 -> bf16 round-to-nearest-even
__device__ __forceinline__ unsigned short f2bf(float f) {
    unsigned u = __builtin_bit_cast(unsigned, f);
    u += 0x7FFFu + ((u >> 16) & 1u);
    return (unsigned short)(u >> 16);
}

// async global->LDS, 16 B/lane; LDS dest = wave-uniform base + lane*16.
__device__ __forceinline__ void gll16(const void* g, void* l) {
    __builtin_amdgcn_global_load_lds(
        (const __attribute__((address_space(1))) unsigned int*)g,
        (__attribute__((address_space(3))) unsigned int*)l, 16, 0, 0);
}

#define VMCNT(n) asm volatile("s_waitcnt vmcnt(%0)" :: "i"(n) : "memory")
// compiler fence after raw s_barrier: stops IR/sched from hoisting the
// phase's ds_reads above the barrier / our counted vmcnt.
#define PHASE_FENCE() do { asm volatile("" ::: "memory"); \
                           __builtin_amdgcn_sched_barrier(0); } while (0)

// ---------------------------------------------------------------------------
// ROUND 12: 8-wave, BK=64, 4-phase counted-vmcnt pipeline (T2+T3+T4+T5).
//
// r11 diagnosis: the 2-barrier-per-BK32 reg-staged loop is serialization-
// bound: all pipes <25% busy, 76us vs 13.8us MFMA floor on scores. Fix is
// the guide's 8-phase-class schedule: raw s_barrier (no vmcnt(0) drain),
// global_load_lds staging of HALF-tiles interleaved with compute phases,
// vmcnt(6) counted waits so loads stay in flight ACROSS barriers.
//
//   C = A @ B^T-layout-B.  A: [M x K] bf16 (k contig, lda); B: [N x K] (ldb)
//
// Geometry (template): BM = 64*AMT, BN = 128*BNT, BK = 64, 512 thr = 8 waves
// arranged 2(m-groups g2) x 4(n-groups nb). Per-wave output = 2 A-parts x
// 2 B-parts; A-part = AMT frags (16 rows each), B-part = BNT frags.
//   row(mt) = (mt/AMT)*(BM/2) + g2*16*AMT + (mt%AMT)*16   (mt in [0,2*AMT))
//   col(nt) = (nt/BNT)*(BN/2) + nb*16*BNT + (nt%BNT)*16
// LDS: 2 bufs x (A BM*128B + B BN*128B): <4,2> = 128 KB, <2,2> = 96 KB.
//
// Per K-tile t (buf bs=t&1), 4 phases; phase = {stage one half-tile of a
// future K-tile; vmcnt(6); s_barrier; fence; ds_read frags; MFMA quadrant}:
//   ph1: stage A-hi(t+1) | read A-lo+B-lo | mma(lo,lo)   [12 ds_read_b128]
//   ph2: stage B-hi(t+1) | read B-hi      | mma(lo,hi)
//   ph3: stage A-lo(t+2) | read A-hi      | mma(hi,lo)   [B-lo frags reused]
//   ph4: stage B-lo(t+2) |                | mma(hi,hi)
// Safety (verified by issue/force chain): with per-wave loads/half = AGL or
// BGL, uniform vmcnt(6) forces the half staged 4 phases earlier BEFORE the
// phase's barrier; every read uses halves staged >=4 phases back. WAR: every
// staged region's last LDS read is >=2 phases earlier (>=1 barrier between
// all waves' reads retiring and the stage issue). Tail: stages are skipped,
// so last iter ph1 waits vmcnt(AGL+BGL) (forces A-lo/B-lo of the last tile),
// ph2 waits vmcnt(0). Prologue stages {Alo0,Blo0,Ahi0,Bhi0,Alo1,Blo1}.
//
// LDS swizzle (r5-r11 scheme extended to 128B rows): physical 16B chunk p of
// row r holds logical chunk p ^ (r&7); applied on the global source column
// (gll dest must be linear), undone at ds_read via c0 ^ (kk<<6). Fragment
// read spreads 64 lanes uniformly over all 32 banks (8 lanes per 16B chunk
// column = 2/bank/round = conflict-free).
//
// Epilogues identical in math to r11 (absmax 0.00195 verified there):
//  mode 3: QKV fused; tn<4 -> bf16 Q|K to Cv (ldc=1024); tn>=4 -> V
//          transposed+packed ushort4 to Cv2 [b][d][s].
//  mode 1: e = exp(acc*scale) (no max-sub), bf16 to Cv; per-wave 64-col
//          partial rowsums plain-stored to rs_part[b][row][32],
//          slot = tn*4 + nb (exactly one writer per slot).
//  mode 0: PV as O^T (m=d, n=q); float4 stores normalized by
//          1/sum(rs_part[q][0..31]).
// Grid: batch = blockIdx % nbatch pins each batch to one XCD's L2.
// ---------------------------------------------------------------------------
template<int AMT, int BNT>
__global__ __launch_bounds__(512, 2) void gemm8(
    const unsigned short* __restrict__ A,
    const unsigned short* __restrict__ B,
    void* __restrict__ Cv,
    unsigned short* __restrict__ Cv2,
    float* __restrict__ rs_part,
    int K, int lda, int ldb, int ldc,
    long long sA, long long sB, long long sC,
    float scale, int mode, int ntn, int nbatch)
{
    constexpr int BM     = 64 * AMT;
    constexpr int BN     = 128 * BNT;
    constexpr int ABYTES = BM * 128;          // per-buf A bytes (BK=64 bf16)
    constexpr int BBYTES = BN * 128;
    constexpr int AH     = ABYTES / 2;        // half-tile bytes
    constexpr int BH     = BBYTES / 2;
    constexpr int AGL    = AMT / 2;           // gll insts per wave per A-half
    constexpr int BGL    = BNT;               // ... per B-half
    constexpr int BUFB   = ABYTES + BBYTES;
    __shared__ __align__(16) char lds[2 * BUFB];

    const int lin = blockIdx.x;
    const int bz  = lin % nbatch;             // batch -> XCD pin
    const int tq  = lin / nbatch;
    const int tn  = tq % ntn;
    const int tm  = tq / ntn;
    A += (long long)bz * sA;
    B += (long long)bz * sB;
    const int m0   = tm * BM;
    const int n0   = tn * BN;
    const int tid  = threadIdx.x;
    const int lane = tid & 63;
    const int w    = tid >> 6;
    const int g2   = w >> 2;                  // m-group (0..1)
    const int nb   = w & 3;                   // n-group (0..3)

    // ---- staging addressing: linear LDS dest, swizzled global source ----
    const int lrow = lane >> 3;                       // 0..7
    const int swz  = ((lane & 7) ^ lrow) << 3;        // source col swizzle
    const unsigned short* gA[2][AGL];
    const unsigned short* gB[2][BGL];
    #pragma unroll
    for (int h = 0; h < 2; ++h) {
        #pragma unroll
        for (int i = 0; i < AGL; ++i)
            gA[h][i] = A + (size_t)(m0 + h * (BM / 2) + (w * AGL + i) * 8 + lrow) * lda + swz;
        #pragma unroll
        for (int i = 0; i < BGL; ++i)
            gB[h][i] = B + (size_t)(n0 + h * (BN / 2) + (w * BGL + i) * 8 + lrow) * ldb + swz;
    }
    auto stA = [&](int bs, int h, int kof) {
        #pragma unroll
        for (int i = 0; i < AGL; ++i)
            gll16(gA[h][i] + kof, lds + bs * BUFB + h * AH + (w * AGL + i) * 1024);
    };
    auto stB = [&](int bs, int h, int kof) {
        #pragma unroll
        for (int i = 0; i < BGL; ++i)
            gll16(gB[h][i] + kof, lds + bs * BUFB + ABYTES + h * BH + (w * BGL + i) * 1024);
    };

    // ---- fragment read addressing (un-swizzle at read) ----
    const int fr = lane & 15;
    const int gq = lane >> 4;
    const int c0 = (gq ^ (fr & 7)) << 4;      // 16B chunk for kk=0; ^64 for kk=1
    int aoff[AMT], boff[BNT];
    #pragma unroll
    for (int ml = 0; ml < AMT; ++ml)
        aoff[ml] = (g2 * (16 * AMT) + ml * 16 + fr) * 128 + c0;
    #pragma unroll
    for (int nl = 0; nl < BNT; ++nl)
        boff[nl] = (nb * (16 * BNT) + nl * 16 + fr) * 128 + c0;

    bf16x8 af[2 * AMT], bLO[2 * BNT], bHI[2 * BNT];
    f32x4 acc[2 * AMT][2 * BNT] = {};

    auto ldA = [&](const char* Ab, int mh) {
        #pragma unroll
        for (int ml = 0; ml < AMT; ++ml)
            #pragma unroll
            for (int kk = 0; kk < 2; ++kk)
                af[ml * 2 + kk] = *(const bf16x8*)(Ab + mh * AH + (aoff[ml] ^ (kk << 6)));
    };
    auto ldB = [&](const char* Bb, int nh, bf16x8* bf) {
        #pragma unroll
        for (int nl = 0; nl < BNT; ++nl)
            #pragma unroll
            for (int kk = 0; kk < 2; ++kk)
                bf[nl * 2 + kk] = *(const bf16x8*)(Bb + nh * BH + (boff[nl] ^ (kk << 6)));
    };
    auto mma = [&](int mh, int nh, const bf16x8* bf) {
        __builtin_amdgcn_s_setprio(1);
        #pragma unroll
        for (int ml = 0; ml < AMT; ++ml)
            #pragma unroll
            for (int nl = 0; nl < BNT; ++nl)
                #pragma unroll
                for (int kk = 0; kk < 2; ++kk)
                    acc[mh * AMT + ml][nh * BNT + nl] =
                        __builtin_amdgcn_mfma_f32_16x16x32_bf16(
                            af[ml * 2 + kk], bf[nl * 2 + kk],
                            acc[mh * AMT + ml][nh * BNT + nl], 0, 0, 0);
        __builtin_amdgcn_s_setprio(0);
    };

    // ---- prologue: tiles 0 fully + A-lo/B-lo of tile 1 ----
    stA(0, 0, 0);  stB(0, 0, 0);
    stA(0, 1, 0);  stB(0, 1, 0);
    stA(1, 0, 64); stB(1, 0, 64);

    const int NT = K >> 6;
    for (int tt = 0; tt < NT; ++tt) {
        const int bs = tt & 1;
        const char* Ab = lds + bs * BUFB;
        const char* Bb = Ab + ABYTES;
        const bool last = (tt == NT - 1);

        // phase 1: (m-lo, n-lo) ; stage A-hi(t+1)
        if (!last) stA(bs ^ 1, 1, (tt + 1) << 6);
        if (last) { VMCNT(AGL + BGL); } else { VMCNT(6); }
        __builtin_amdgcn_s_barrier();
        PHASE_FENCE();
        ldA(Ab, 0); ldB(Bb, 0, bLO);
        mma(0, 0, bLO);

        // phase 2: (m-lo, n-hi) ; stage B-hi(t+1)
        if (!last) stB(bs ^ 1, 1, (tt + 1) << 6);
        if (last) { VMCNT(0); } else { VMCNT(6); }
        __builtin_amdgcn_s_barrier();
        PHASE_FENCE();
        ldB(Bb, 1, bHI);
        mma(0, 1, bHI);

        // phase 3: (m-hi, n-lo) ; stage A-lo(t+2)
        if (tt + 2 < NT) stA(bs, 0, (tt + 2) << 6);
        VMCNT(6);
        __builtin_amdgcn_s_barrier();
        PHASE_FENCE();
        ldA(Ab, 1);
        mma(1, 0, bLO);

        // phase 4: (m-hi, n-hi) ; stage B-lo(t+2)
        if (tt + 2 < NT) stB(bs, 0, (tt + 2) << 6);
        VMCNT(6);
        __builtin_amdgcn_s_barrier();
        PHASE_FENCE();
        mma(1, 1, bHI);
    }

    // ---- epilogue. 16x16 C/D layout (m89-verified): col = lane&15,
    // row = (lane>>4)*4 + r (reg-quad = 4 consecutive rows). ----
    const int rb4 = gq << 2;
#define AB_(mt) ((((mt) / AMT) * (BM / 2)) + g2 * (16 * AMT) + ((mt) % AMT) * 16)
#define BB_(nt) ((((nt) / BNT) * (BN / 2)) + nb * (16 * BNT) + ((nt) % BNT) * 16)

    if (mode == 1) {
        // softmax numerator: e = exp(s*scale), no max subtraction.
        #pragma unroll
        for (int mt = 0; mt < 2 * AMT; ++mt)
            #pragma unroll
            for (int nt = 0; nt < 2 * BNT; ++nt)
                #pragma unroll
                for (int r = 0; r < 4; ++r)
                    acc[mt][nt][r] = __expf(acc[mt][nt][r] * scale);

        unsigned short* C = (unsigned short*)Cv + (long long)bz * sC;
        #pragma unroll
        for (int mt = 0; mt < 2 * AMT; ++mt)
            #pragma unroll
            for (int nt = 0; nt < 2 * BNT; ++nt) {
                const int gc = n0 + BB_(nt) + fr;
                #pragma unroll
                for (int r = 0; r < 4; ++r)
                    C[(size_t)(m0 + AB_(mt) + rb4 + r) * ldc + gc] = f2bf(acc[mt][nt][r]);
            }

        // per-wave 64-col partials; unique slot tn*4 + nb; no atomics.
        float* rp = rs_part + (((long long)bz * S_) << 5) + tn * 4 + nb;
        #pragma unroll
        for (int mt = 0; mt < 2 * AMT; ++mt)
            #pragma unroll
            for (int r = 0; r < 4; ++r) {
                float s = 0.f;
                #pragma unroll
                for (int nt = 0; nt < 2 * BNT; ++nt) s += acc[mt][nt][r];
                s += __shfl_xor(s, 8);
                s += __shfl_xor(s, 4);
                s += __shfl_xor(s, 2);
                s += __shfl_xor(s, 1);
                if (fr == 0)
                    rp[(long long)(m0 + AB_(mt) + rb4 + r) << 5] = s;
            }
    } else if (mode == 3) {
        if (tn >= 4) {
            // V^T packed write: [b][d][s], reg-quad = 4 consecutive s.
            #pragma unroll
            for (int mt = 0; mt < 2 * AMT; ++mt) {
                const int s0q = m0 + AB_(mt) + rb4;
                const int b   = s0q >> 11;            // S_=2048 rows/batch
                const int se  = s0q & (S_ - 1);
                #pragma unroll
                for (int nt = 0; nt < 2 * BNT; ++nt) {
                    const int d = (n0 - 2 * D_) + BB_(nt) + fr;
                    ushort4 u;
                    u.x = f2bf(acc[mt][nt][0]);
                    u.y = f2bf(acc[mt][nt][1]);
                    u.z = f2bf(acc[mt][nt][2]);
                    u.w = f2bf(acc[mt][nt][3]);
                    *(ushort4*)&Cv2[((size_t)b * D_ + d) * S_ + se] = u;
                }
            }
        } else {
            unsigned short* C = (unsigned short*)Cv;
            #pragma unroll
            for (int mt = 0; mt < 2 * AMT; ++mt)
                #pragma unroll
                for (int nt = 0; nt < 2 * BNT; ++nt) {
                    const int gc = n0 + BB_(nt) + fr;
                    #pragma unroll
                    for (int r = 0; r < 4; ++r)
                        C[(size_t)(m0 + AB_(mt) + rb4 + r) * ldc + gc] = f2bf(acc[mt][nt][r]);
                }
        }
    } else {
        // PV as O^T: m = d, n = q; normalize by 1/sum of the 32 partials.
        float* C = (float*)Cv + (long long)bz * sC;
        #pragma unroll
        for (int nt = 0; nt < 2 * BNT; ++nt) {
            const int q = n0 + BB_(nt) + fr;
            const float* rp = rs_part + (((long long)bz * S_ + q) << 5);
            float ssum = 0.f;
            #pragma unroll
            for (int pq = 0; pq < 8; ++pq) {
                const float4 p4 = *(const float4*)(rp + 4 * pq);
                ssum += (p4.x + p4.y) + (p4.z + p4.w);
            }
            const float inv = __builtin_amdgcn_rcpf(ssum);
            #pragma unroll
            for (int mt = 0; mt < 2 * AMT; ++mt) {
                const int d0 = m0 + AB_(mt) + rb4;
                float4 o;
                o.x = acc[mt][nt][0] * inv;
                o.y = acc[mt][nt][1] * inv;
                o.z = acc[mt][nt][2] * inv;
                o.w = acc[mt][nt][3] * inv;
                *(float4*)&C[(size_t)q * ldc + d0] = o;
            }
        }
    }
#undef AB_
#undef BB_
}

// ---------------------------------------------------------------------------
// fp32 -> bf16 convert, 4 elems/thread
// ---------------------------------------------------------------------------
__global__ __launch_bounds__(256) void convert_x4(const float* __restrict__ x,
                                                  unsigned short* __restrict__ xb) {
    const size_t i = ((size_t)blockIdx.x * 256 + threadIdx.x) * 4;
    const float4 f = *(const float4*)(x + i);
    ushort4 u;
    u.x = f2bf(f.x); u.y = f2bf(f.y); u.z = f2bf(f.z); u.w = f2bf(f.w);
    *(ushort4*)(xb + i) = u;
}

// W [D][D] (d,e) -> WT bf16 rows e (n), cols d (k); WQ|WK|WV stack to [3D][D].
__global__ __launch_bounds__(256) void convert_w(const float* __restrict__ WQ,
                                                 const float* __restrict__ WK,
                                                 const float* __restrict__ WV,
                                                 unsigned short* __restrict__ WT) {
    const int o = blockIdx.x * 256 + threadIdx.x;   // 0..D*D-1
    const float* W = blockIdx.y == 0 ? WQ : (blockIdx.y == 1 ? WK : WV);
    const int e = o >> 9, d = o & (D_ - 1);
    WT[(size_t)blockIdx.y * D_ * D_ + o] = f2bf(W[d * D_ + e]);
}

// ---------------------------------------------------------------------------
extern "C" void kernel_launch(void* const* d_in, const int* in_sizes, int n_in,
                              void* d_out, int out_size, void* d_ws, size_t ws_size,
                              hipStream_t stream)
{
    const float* x  = (const float*)d_in[0];
    const float* WQ = (const float*)d_in[1];
    const float* WK = (const float*)d_in[2];
    const float* WV = (const float*)d_in[3];

    // workspace layout (bf16 elements); ~138 MB total
    unsigned short* ws  = (unsigned short*)d_ws;
    const size_t NX = (size_t)B_ * S_ * D_;          // 8,388,608
    unsigned short* xb  = ws;                        // [16384][512]
    unsigned short* wtb = xb + NX;                   // [1536 n][512 k]
    unsigned short* qk  = wtb + 3 * D_ * D_;         // [16384][1024] (Q|K)
    unsigned short* vtb = qk + NX * 2;               // [b][d][s]
    unsigned short* sb  = vtb + NX;                  // [b][q][k] exp-scores
    float* rsp = (float*)(sb + (size_t)B_ * S_ * S_);  // [b][S][32] partials

    // 1) converts (no rowsum zeroing needed: every rs_part slot is written
    //    exactly once by the scores dispatch before PV reads it)
    convert_x4<<<dim3((unsigned)(NX / 4 / 256)), 256, 0, stream>>>(x, xb);
    convert_w<<<dim3(D_ * D_ / 256, 3), 256, 0, stream>>>(WQ, WK, WV, wtb);

    // 2) fused QKV projection, 256x256 tiles: grid 64 x 6 = 384.
    //    tn 0-3: Q|K -> qk (ldc 1024); tn 4-5: V -> vtb transposed.
    gemm8<4, 2><<<dim3(384), 512, 0, stream>>>(
        xb, wtb, qk, vtb, nullptr, D_, D_, D_, 2 * D_,
        0, 0, 0, 1.0f, 3, /*ntn*/ 6, /*nbatch*/ 1);

    // 3) e = exp(Q K^T / sqrt(D)) -> sb, partial row sums -> rsp.
    //    256x256 tiles: 8 batches x 8 x 8 = 512 blocks, batch->XCD pinned.
    gemm8<4, 2><<<dim3(512), 512, 0, stream>>>(
        qk /*Q*/, qk + D_ /*K*/, sb, nullptr, rsp, D_, 2 * D_, 2 * D_, S_,
        (long long)S_ * 2 * D_, (long long)S_ * 2 * D_, (long long)S_ * S_,
        0.04419417382415922f, 1, /*ntn*/ 8, /*nbatch*/ 8);

    // 4) O^T = V^T @ P^T, 128x256 tiles: 8 x 4 x 8 = 256 blocks (full chip,
    //    one round). float4 stores to out[b][q][d] with 1/rowsum.
    gemm8<2, 2><<<dim3(256), 512, 0, stream>>>(
        vtb, sb, d_out, nullptr, rsp, S_, S_, S_, D_,
        (long long)D_ * S_, (long long)S_ * S_, (long long)S_ * D_,
        1.0f, 0, /*ntn*/ 8, /*nbatch*/ 8);
}